// Round 1
// baseline (22191.667 us; speedup 1.0000x reference)
//
#include <hip/hip_runtime.h>

typedef _Float16 f16;
typedef _Float16 f16x2 __attribute__((ext_vector_type(2)));
typedef _Float16 f16x4 __attribute__((ext_vector_type(4)));
typedef _Float16 f16x8 __attribute__((ext_vector_type(8)));
typedef float f32x4 __attribute__((ext_vector_type(4)));

#define S_LEN 1024
#define BATCH 32
#define HID 256

#if __has_builtin(__builtin_amdgcn_fdot2)
#define FDOT2(a, b, c) __builtin_amdgcn_fdot2((a), (b), (c), false)
#else
static __device__ __forceinline__ float FDOT2(f16x2 a, f16x2 b, float c) {
  return c + (float)a[0] * (float)b[0] + (float)a[1] * (float)b[1];
}
#endif

__device__ __forceinline__ float dot8(f16x8 w, f16x8 h, float acc) {
  f16x2 a, b;
  a[0] = w[0]; a[1] = w[1]; b[0] = h[0]; b[1] = h[1]; acc = FDOT2(a, b, acc);
  a[0] = w[2]; a[1] = w[3]; b[0] = h[2]; b[1] = h[3]; acc = FDOT2(a, b, acc);
  a[0] = w[4]; a[1] = w[5]; b[0] = h[4]; b[1] = h[5]; acc = FDOT2(a, b, acc);
  a[0] = w[6]; a[1] = w[7]; b[0] = h[6]; b[1] = h[7]; acc = FDOT2(a, b, acc);
  return acc;
}

__device__ __forceinline__ float sigf(float x) { return 1.f / (1.f + __expf(-x)); }
__device__ __forceinline__ float tanhf_(float x) { return 1.f - 2.f / (__expf(2.f * x) + 1.f); }

// ---------------- f32 -> f16 convert (n4 = n/4 float4 groups) ----------------
__global__ void cvt_f32_f16(const float* __restrict__ src, f16* __restrict__ dst, int n4) {
  int i = blockIdx.x * 256 + threadIdx.x;
  if (i < n4) {
    float4 v = ((const float4*)src)[i];
    f16x4 h;
    h[0] = (f16)v.x; h[1] = (f16)v.y; h[2] = (f16)v.z; h[3] = (f16)v.w;
    ((f16x4*)dst)[i] = h;
  }
}

// ---------------- input-projection GEMM ----------------
// P[t][b][n] = sum_k A[b*S+t][k] * W[n][k] + bih[n] + bhh[n]   (A: (B*S, K) f32, W: (1024, K) f32)
// 128x128 tile, BK=64, 256 threads (4 waves 2x2), mfma_f32_16x16x32_f16, reg-staged f32->f16.
__global__ __launch_bounds__(256) void proj_gemm(const float* __restrict__ A,
                                                 const float* __restrict__ W,
                                                 const float* __restrict__ bih,
                                                 const float* __restrict__ bhh,
                                                 f16* __restrict__ P, int K) {
  __shared__ f16 As[128 * 64];
  __shared__ f16 Bs[128 * 64];
  const int tid = threadIdx.x;
  const int bn = blockIdx.x;   // 0..7   (n-fastest: A panel stays L2-hot)
  const int bm = blockIdx.y;   // 0..255
  const int lane = tid & 63, wid = tid >> 6;
  const int wm = wid >> 1, wn = wid & 1;
  const int lr = lane & 15, lk = lane >> 4;

  f32x4 acc[4][4];
#pragma unroll
  for (int i = 0; i < 4; ++i)
#pragma unroll
    for (int j = 0; j < 4; ++j) acc[i][j] = (f32x4){0.f, 0.f, 0.f, 0.f};

  for (int k0 = 0; k0 < K; k0 += 64) {
#pragma unroll
    for (int s = 0; s < 4; ++s) {
      int slot = s * 256 + tid;
      int row = slot >> 3, seg = slot & 7;
      {
        const float* ga = A + (size_t)(bm * 128 + row) * K + (k0 + seg * 8);
        float4 v0 = *(const float4*)ga;
        float4 v1 = *(const float4*)(ga + 4);
        f16x8 h;
        h[0] = (f16)v0.x; h[1] = (f16)v0.y; h[2] = (f16)v0.z; h[3] = (f16)v0.w;
        h[4] = (f16)v1.x; h[5] = (f16)v1.y; h[6] = (f16)v1.z; h[7] = (f16)v1.w;
        *(f16x8*)(&As[slot * 8]) = h;
      }
      {
        const float* gb = W + (size_t)(bn * 128 + row) * K + (k0 + seg * 8);
        float4 v0 = *(const float4*)gb;
        float4 v1 = *(const float4*)(gb + 4);
        f16x8 h;
        h[0] = (f16)v0.x; h[1] = (f16)v0.y; h[2] = (f16)v0.z; h[3] = (f16)v0.w;
        h[4] = (f16)v1.x; h[5] = (f16)v1.y; h[6] = (f16)v1.z; h[7] = (f16)v1.w;
        *(f16x8*)(&Bs[slot * 8]) = h;
      }
    }
    __syncthreads();
#pragma unroll
    for (int kk = 0; kk < 64; kk += 32) {
      f16x8 af[4], bf[4];
#pragma unroll
      for (int mi = 0; mi < 4; ++mi)
        af[mi] = *(const f16x8*)(&As[(wm * 64 + mi * 16 + lr) * 64 + kk + lk * 8]);
#pragma unroll
      for (int ni = 0; ni < 4; ++ni)
        bf[ni] = *(const f16x8*)(&Bs[(wn * 64 + ni * 16 + lr) * 64 + kk + lk * 8]);
#pragma unroll
      for (int mi = 0; mi < 4; ++mi)
#pragma unroll
        for (int ni = 0; ni < 4; ++ni)
          acc[mi][ni] = __builtin_amdgcn_mfma_f32_16x16x32_f16(af[mi], bf[ni], acc[mi][ni], 0, 0, 0);
    }
    __syncthreads();
  }

#pragma unroll
  for (int ni = 0; ni < 4; ++ni) {
    int col = bn * 128 + wn * 64 + ni * 16 + lr;
    float bias = bih[col] + bhh[col];
#pragma unroll
    for (int mi = 0; mi < 4; ++mi) {
#pragma unroll
      for (int r = 0; r < 4; ++r) {
        int rowg = bm * 128 + wm * 64 + mi * 16 + lk * 4 + r;
        int t = rowg & 1023, bb = rowg >> 10;  // rows are b*S + t, S=1024
        P[(size_t)((t << 5) + bb) * 1024 + col] = (f16)(acc[mi][ni][r] + bias);
      }
    }
  }
}

// ---------------- LSTM recurrence ----------------
// 1 block per (unit u in {main_f, main_b, bin_f, bin_b}, batch b). 1024 threads;
// thread j owns gate-row j; whh (f16, L2-resident) streamed each step; gates via LDS.
__global__ __launch_bounds__(1024) void lstm_rec(const f16* __restrict__ whh4,
                                                 const f16* __restrict__ Pall,
                                                 const float* __restrict__ h0m,
                                                 const float* __restrict__ c0m,
                                                 const float* __restrict__ h0b,
                                                 const float* __restrict__ c0b,
                                                 f16* __restrict__ hid4) {
  const int u = blockIdx.x >> 5;
  const int b = blockIdx.x & 31;
  const int tid = threadIdx.x;
  const int dir = u & 1;
  const f16* __restrict__ Wr = whh4 + ((size_t)u << 18) + (size_t)tid * 256;
  const f16* __restrict__ Pu = Pall + ((size_t)u << 25);
  __shared__ __align__(16) f16 hs[256];
  __shared__ float zs[1024];
  float c = 0.f;
  if (tid < 256) {
    const float* h0 = (u < 2 ? h0m : h0b) + (size_t)dir * BATCH * HID + b * HID;
    const float* c0 = (u < 2 ? c0m : c0b) + (size_t)dir * BATCH * HID + b * HID;
    hs[tid] = (f16)h0[tid];
    c = c0[tid];
  }
  __syncthreads();
  const f16x8* __restrict__ w8 = (const f16x8*)Wr;
  const f16x8* h8 = (const f16x8*)hs;
  for (int s = 0; s < S_LEN; ++s) {
    const int t = dir ? (S_LEN - 1 - s) : s;
    float acc = (float)Pu[(size_t)((t << 5) + b) * 1024 + tid];
#pragma unroll 8
    for (int kc = 0; kc < 32; ++kc) acc = dot8(w8[kc], h8[kc], acc);
    zs[tid] = acc;
    __syncthreads();
    if (tid < 256) {
      float zi = zs[tid], zf = zs[tid + 256], zg = zs[tid + 512], zo = zs[tid + 768];
      c = sigf(zf) * c + sigf(zi) * tanhf_(zg);
      float h = sigf(zo) * tanhf_(c);
      hs[tid] = (f16)h;
      hid4[((size_t)b << 20) + ((size_t)t << 10) + (u << 8) + tid] = (f16)h;
    }
    __syncthreads();
  }
}

// ---------------- emissions ----------------
// emis[row][n] = hid4[row][:] . wtag[n][:] + btag[n]   (row = b*S + t)
// emisb[row][n] = hid4[row][512:1024] . wbin[n][:] + bbin[n]
__global__ __launch_bounds__(256) void emis_kernel(const f16* __restrict__ hid4,
                                                   const f16* __restrict__ wtag,
                                                   const float* __restrict__ btag,
                                                   const f16* __restrict__ wbin,
                                                   const float* __restrict__ bbin,
                                                   float* __restrict__ emis,
                                                   float* __restrict__ emisb) {
  const int tid = threadIdx.x;
  const int rl = tid >> 4, n = tid & 15;
  const size_t row = (size_t)blockIdx.x * 16 + rl;
  const f16x8* hv = (const f16x8*)(hid4 + row * 1024);
  const f16x8* wv = (const f16x8*)(wtag + n * 1024);
  float acc = btag[n];
#pragma unroll 8
  for (int kc = 0; kc < 128; ++kc) acc = dot8(wv[kc], hv[kc], acc);
  emis[row * 16 + n] = acc;
  if (n < 5) {
    const f16x8* hv2 = (const f16x8*)(hid4 + row * 1024 + 512);
    const f16x8* wv2 = (const f16x8*)(wbin + (size_t)n * 512);
    float a2 = bbin[n];
#pragma unroll 8
    for (int kc = 0; kc < 64; ++kc) a2 = dot8(wv2[kc], hv2[kc], a2);
    emisb[row * 5 + n] = a2;
  }
}

// ---------------- CRF forward (logZ) ----------------
// 1 block (64 threads) per (crf, batch). lane = j*4 + p; each lane handles 4 source tags.
__global__ __launch_bounds__(64) void crf_logz(const float* __restrict__ emis,
                                               const float* __restrict__ trans,
                                               const float* __restrict__ emisb,
                                               const float* __restrict__ transb,
                                               const float* __restrict__ mask,
                                               float* __restrict__ outLogZ) {
  const int crf = blockIdx.x >> 5, b = blockIdx.x & 31;
  const int NTc = crf ? 5 : 16;
  const float* __restrict__ E = crf ? emisb : emis;
  const float* __restrict__ T = crf ? transb : trans;
  const int lane = threadIdx.x;
  const int j = lane >> 2, p = lane & 3;
  const bool jv = (j < NTc);
  float Tc[4];
#pragma unroll
  for (int ii = 0; ii < 4; ++ii) {
    int i = p * 4 + ii;
    Tc[ii] = (jv && i < NTc) ? T[i * NTc + j] : -1e30f;
  }
  __shared__ float as_[16];
  float alpha = 0.f;
  if (jv && p == 0) {
    alpha = T[1 * NTc + j] + E[(size_t)(b << 10) * NTc + j];  // SOS=1, t=0
    as_[j] = alpha;
  }
  __syncthreads();
  for (int t = 1; t < S_LEN; ++t) {
    float m_t = mask[(b << 10) + t];
    float v[4];
#pragma unroll
    for (int ii = 0; ii < 4; ++ii) {
      int i = p * 4 + ii;
      v[ii] = (jv && i < NTc) ? (as_[i] + Tc[ii]) : -1e30f;
    }
    float mx = fmaxf(fmaxf(v[0], v[1]), fmaxf(v[2], v[3]));
    mx = fmaxf(mx, __shfl_xor(mx, 1, 4));
    mx = fmaxf(mx, __shfl_xor(mx, 2, 4));
    float ssum = __expf(v[0] - mx) + __expf(v[1] - mx) + __expf(v[2] - mx) + __expf(v[3] - mx);
    ssum += __shfl_xor(ssum, 1, 4);
    ssum += __shfl_xor(ssum, 2, 4);
    if (jv && p == 0) {
      float e_tj = E[((size_t)(b << 10) + t) * NTc + j];
      float newv = e_tj + mx + __logf(ssum);
      alpha = (m_t > 0.5f) ? newv : alpha;
    }
    __syncthreads();
    if (jv && p == 0) as_[j] = alpha;
    __syncthreads();
  }
  if (lane == 0) {
    float mx = -1e30f;
    for (int jj = 0; jj < NTc; ++jj) mx = fmaxf(mx, as_[jj] + T[jj * NTc + 2]);  // EOS=2
    float ssum = 0.f;
    for (int jj = 0; jj < NTc; ++jj) ssum += __expf(as_[jj] + T[jj * NTc + 2] - mx);
    outLogZ[crf * 32 + b] = mx + __logf(ssum);
  }
}

// ---------------- CRF gold score ----------------
__global__ __launch_bounds__(64) void crf_score(const float* __restrict__ emis,
                                                const float* __restrict__ trans,
                                                const float* __restrict__ emisb,
                                                const float* __restrict__ transb,
                                                const float* __restrict__ mask,
                                                const int* __restrict__ tags,
                                                const int* __restrict__ tagsb,
                                                float* __restrict__ outScore) {
  const int crf = blockIdx.x >> 5, b = blockIdx.x & 31;
  const int NTc = crf ? 5 : 16;
  const float* __restrict__ E = crf ? emisb : emis;
  const float* __restrict__ T = crf ? transb : trans;
  const int* __restrict__ tg = (crf ? tagsb : tags) + (b << 10);
  const float* __restrict__ mk = mask + (b << 10);
  const int lane = threadIdx.x;
  float s = 0.f, cnt = 0.f;
  for (int t = lane; t < S_LEN; t += 64) {
    float m = mk[t];
    cnt += m;
    if (t >= 1 && m > 0.5f)
      s += E[((size_t)(b << 10) + t) * NTc + tg[t]] + T[tg[t - 1] * NTc + tg[t]];
  }
#pragma unroll
  for (int off = 32; off >= 1; off >>= 1) {
    s += __shfl_down(s, off);
    cnt += __shfl_down(cnt, off);
  }
  if (lane == 0) {
    int L = (int)(cnt + 0.5f);
    int t0 = tg[0];
    float tot = T[1 * NTc + t0] + E[(size_t)(b << 10) * NTc + t0] + s + T[tg[L - 1] * NTc + 2];
    outScore[crf * 32 + b] = tot;
  }
}

__global__ void finalk(const float* __restrict__ logZ, const float* __restrict__ score,
                       float* __restrict__ out) {
  int j = threadIdx.x;
  if (j < 2) {
    float a = 0.f;
    for (int b = 0; b < 32; ++b) a += logZ[j * 32 + b] - score[j * 32 + b];
    out[j] = a;  // nll = sum(logZ - score)
  }
}

extern "C" void kernel_launch(void* const* d_in, const int* in_sizes, int n_in,
                              void* d_out, int out_size, void* d_ws, size_t ws_size,
                              hipStream_t stream) {
  const float* x       = (const float*)d_in[0];
  const float* xbin    = (const float*)d_in[1];
  const float* mask    = (const float*)d_in[2];
  const int*   tags    = (const int*)d_in[3];
  const int*   tagsb   = (const int*)d_in[4];
  const float* trans   = (const float*)d_in[5];
  const float* transb  = (const float*)d_in[6];
  const float* w2f_ih  = (const float*)d_in[7];
  const float* w2f_hh  = (const float*)d_in[8];
  const float* b2f_ih  = (const float*)d_in[9];
  const float* b2f_hh  = (const float*)d_in[10];
  const float* w2b_ih  = (const float*)d_in[11];
  const float* w2b_hh  = (const float*)d_in[12];
  const float* b2b_ih  = (const float*)d_in[13];
  const float* b2b_hh  = (const float*)d_in[14];
  const float* w_bin   = (const float*)d_in[15];
  const float* bb_bin  = (const float*)d_in[16];
  const float* w1f_ih  = (const float*)d_in[17];
  const float* w1f_hh  = (const float*)d_in[18];
  const float* b1f_ih  = (const float*)d_in[19];
  const float* b1f_hh  = (const float*)d_in[20];
  const float* w1b_ih  = (const float*)d_in[21];
  const float* w1b_hh  = (const float*)d_in[22];
  const float* b1b_ih  = (const float*)d_in[23];
  const float* b1b_hh  = (const float*)d_in[24];
  const float* w_tag   = (const float*)d_in[25];
  const float* b_tag   = (const float*)d_in[26];
  const float* h0_bin  = (const float*)d_in[27];
  const float* c0_bin  = (const float*)d_in[28];
  const float* h0_main = (const float*)d_in[29];
  const float* c0_main = (const float*)d_in[30];

  char* ws = (char*)d_ws;
  f16* P      = (f16*)(ws);                     // 4 units x 33554432 f16 = 256 MiB
  f16* hid4   = (f16*)(ws + 268435456);         // (B*S, 1024) f16 = 64 MiB
  f16* whh4   = (f16*)(ws + 335544320);         // 4 x 262144 f16
  f16* wtag   = (f16*)(ws + 337641472);         // 16384 f16
  f16* wbin   = (f16*)(ws + 337674240);         // 2560 f16
  float* emis  = (float*)(ws + 337679360);      // 32768*16 f32
  float* emisb = (float*)(ws + 339776512);      // 32768*5 f32
  float* logZ  = (float*)(ws + 340431872);      // 64 f32
  float* score = (float*)(ws + 340432128);      // 64 f32

  // weight converts (f32 -> f16)
  cvt_f32_f16<<<256, 256, 0, stream>>>(w1f_hh, whh4 + 0 * 262144, 65536);
  cvt_f32_f16<<<256, 256, 0, stream>>>(w1b_hh, whh4 + 1 * 262144, 65536);
  cvt_f32_f16<<<256, 256, 0, stream>>>(w2f_hh, whh4 + 2 * 262144, 65536);
  cvt_f32_f16<<<256, 256, 0, stream>>>(w2b_hh, whh4 + 3 * 262144, 65536);
  cvt_f32_f16<<<16, 256, 0, stream>>>(w_tag, wtag, 4096);
  cvt_f32_f16<<<3, 256, 0, stream>>>(w_bin, wbin, 640);

  // input projections: units 0..3 = main_f, main_b, bin_f, bin_b
  dim3 gg(8, 256);
  proj_gemm<<<gg, 256, 0, stream>>>(x, w1f_ih, b1f_ih, b1f_hh, P + (size_t)0 * 33554432, 512);
  proj_gemm<<<gg, 256, 0, stream>>>(x, w1b_ih, b1b_ih, b1b_hh, P + (size_t)1 * 33554432, 512);
  proj_gemm<<<gg, 256, 0, stream>>>(xbin, w2f_ih, b2f_ih, b2f_hh, P + (size_t)2 * 33554432, 1536);
  proj_gemm<<<gg, 256, 0, stream>>>(xbin, w2b_ih, b2b_ih, b2b_hh, P + (size_t)3 * 33554432, 1536);

  lstm_rec<<<128, 1024, 0, stream>>>(whh4, P, h0_main, c0_main, h0_bin, c0_bin, hid4);
  emis_kernel<<<2048, 256, 0, stream>>>(hid4, wtag, b_tag, wbin, bb_bin, emis, emisb);
  crf_logz<<<64, 64, 0, stream>>>(emis, trans, emisb, transb, mask, logZ);
  crf_score<<<64, 64, 0, stream>>>(emis, trans, emisb, transb, mask, tags, tagsb, score);
  finalk<<<1, 64, 0, stream>>>(logZ, score, (float*)d_out);
}

// Round 3
// 4143.356 us; speedup vs baseline: 5.3560x; 5.3560x over previous
//
#include <hip/hip_runtime.h>
#if __has_include(<hip/hip_fp8.h>)
#include <hip/hip_fp8.h>
#define HAVE_HIP_FP8 1
#endif

typedef _Float16 f16;
typedef _Float16 f16x2 __attribute__((ext_vector_type(2)));
typedef _Float16 f16x4 __attribute__((ext_vector_type(4)));
typedef _Float16 f16x8 __attribute__((ext_vector_type(8)));
typedef float f32x4 __attribute__((ext_vector_type(4)));

#define S_LEN 1024
#define BATCH 32
#define HID 256
#define L2E 1.4426950408889634f
#define L2E2 2.8853900817779268f

#if __has_builtin(__builtin_amdgcn_fdot2)
#define FDOT2(a, b, c) __builtin_amdgcn_fdot2((a), (b), (c), false)
#else
static __device__ __forceinline__ float FDOT2(f16x2 a, f16x2 b, float c) {
  return c + (float)a[0] * (float)b[0] + (float)a[1] * (float)b[1];
}
#endif

__device__ __forceinline__ float EXP2(float x) {
#if __has_builtin(__builtin_amdgcn_exp2f)
  return __builtin_amdgcn_exp2f(x);
#else
  return exp2f(x);
#endif
}
__device__ __forceinline__ float RCP(float x) {
#if __has_builtin(__builtin_amdgcn_rcpf)
  return __builtin_amdgcn_rcpf(x);
#else
  return 1.0f / x;
#endif
}

__device__ __forceinline__ int PK_FP8(float a, float b) {
#if __has_builtin(__builtin_amdgcn_cvt_pk_fp8_f32)
  return __builtin_amdgcn_cvt_pk_fp8_f32(a, b, 0, false);
#elif defined(HAVE_HIP_FP8)
  __hip_fp8_e4m3 fa(a), fb(b);
  return (int)fa.__x | ((int)fb.__x << 8);
#else
#error "no fp8 conversion path on this target"
#endif
}

__device__ __forceinline__ float dot8(f16x8 w, f16x8 h, float acc) {
  f16x2 a, b;
  a[0] = w[0]; a[1] = w[1]; b[0] = h[0]; b[1] = h[1]; acc = FDOT2(a, b, acc);
  a[0] = w[2]; a[1] = w[3]; b[0] = h[2]; b[1] = h[3]; acc = FDOT2(a, b, acc);
  a[0] = w[4]; a[1] = w[5]; b[0] = h[4]; b[1] = h[5]; acc = FDOT2(a, b, acc);
  a[0] = w[6]; a[1] = w[7]; b[0] = h[6]; b[1] = h[7]; acc = FDOT2(a, b, acc);
  return acc;
}

// ---------------- f32 -> f16 convert ----------------
__global__ void cvt_f32_f16(const float* __restrict__ src, f16* __restrict__ dst, int n4) {
  int i = blockIdx.x * 256 + threadIdx.x;
  if (i < n4) {
    float4 v = ((const float4*)src)[i];
    f16x4 h;
    h[0] = (f16)v.x; h[1] = (f16)v.y; h[2] = (f16)v.z; h[3] = (f16)v.w;
    ((f16x4*)dst)[i] = h;
  }
}

// ---------------- whh f32 -> fp8 e4m3, pre-scaled by log2e (2*log2e for g-rows) ----------------
__global__ void cvt_whh_fp8(const float* __restrict__ src, unsigned char* __restrict__ dst) {
  int i = blockIdx.x * 256 + threadIdx.x;  // pair index, 131072 pairs
  if (i < 131072) {
    int n = (i * 2) >> 8;  // gate row 0..1023
    float sc = (n >= 512 && n < 768) ? L2E2 : L2E;
    float a = src[i * 2] * sc, b = src[i * 2 + 1] * sc;
    int pk = PK_FP8(a, b);
    dst[i * 2] = (unsigned char)(pk & 0xff);
    dst[i * 2 + 1] = (unsigned char)((pk >> 8) & 0xff);
  }
}

// ---------------- input-projection GEMM (outputs log2e-scaled z) ----------------
__global__ __launch_bounds__(256) void proj_gemm(const float* __restrict__ A,
                                                 const float* __restrict__ W,
                                                 const float* __restrict__ bih,
                                                 const float* __restrict__ bhh,
                                                 f16* __restrict__ P, int K) {
  __shared__ f16 As[128 * 64];
  __shared__ f16 Bs[128 * 64];
  const int tid = threadIdx.x;
  const int bn = blockIdx.x;   // 0..7
  const int bm = blockIdx.y;   // 0..255
  const int lane = tid & 63, wid = tid >> 6;
  const int wm = wid >> 1, wn = wid & 1;
  const int lr = lane & 15, lk = lane >> 4;

  f32x4 acc[4][4];
#pragma unroll
  for (int i = 0; i < 4; ++i)
#pragma unroll
    for (int j = 0; j < 4; ++j) acc[i][j] = (f32x4){0.f, 0.f, 0.f, 0.f};

  for (int k0 = 0; k0 < K; k0 += 64) {
#pragma unroll
    for (int s = 0; s < 4; ++s) {
      int slot = s * 256 + tid;
      int row = slot >> 3, seg = slot & 7;
      {
        const float* ga = A + (size_t)(bm * 128 + row) * K + (k0 + seg * 8);
        float4 v0 = *(const float4*)ga;
        float4 v1 = *(const float4*)(ga + 4);
        f16x8 h;
        h[0] = (f16)v0.x; h[1] = (f16)v0.y; h[2] = (f16)v0.z; h[3] = (f16)v0.w;
        h[4] = (f16)v1.x; h[5] = (f16)v1.y; h[6] = (f16)v1.z; h[7] = (f16)v1.w;
        *(f16x8*)(&As[slot * 8]) = h;
      }
      {
        int ng = bn * 128 + row;
        float sc = (ng >= 512 && ng < 768) ? L2E2 : L2E;
        const float* gb = W + (size_t)ng * K + (k0 + seg * 8);
        float4 v0 = *(const float4*)gb;
        float4 v1 = *(const float4*)(gb + 4);
        f16x8 h;
        h[0] = (f16)(v0.x * sc); h[1] = (f16)(v0.y * sc); h[2] = (f16)(v0.z * sc); h[3] = (f16)(v0.w * sc);
        h[4] = (f16)(v1.x * sc); h[5] = (f16)(v1.y * sc); h[6] = (f16)(v1.z * sc); h[7] = (f16)(v1.w * sc);
        *(f16x8*)(&Bs[slot * 8]) = h;
      }
    }
    __syncthreads();
#pragma unroll
    for (int kk = 0; kk < 64; kk += 32) {
      f16x8 af[4], bf[4];
#pragma unroll
      for (int mi = 0; mi < 4; ++mi)
        af[mi] = *(const f16x8*)(&As[(wm * 64 + mi * 16 + lr) * 64 + kk + lk * 8]);
#pragma unroll
      for (int ni = 0; ni < 4; ++ni)
        bf[ni] = *(const f16x8*)(&Bs[(wn * 64 + ni * 16 + lr) * 64 + kk + lk * 8]);
#pragma unroll
      for (int mi = 0; mi < 4; ++mi)
#pragma unroll
        for (int ni = 0; ni < 4; ++ni)
          acc[mi][ni] = __builtin_amdgcn_mfma_f32_16x16x32_f16(af[mi], bf[ni], acc[mi][ni], 0, 0, 0);
    }
    __syncthreads();
  }

#pragma unroll
  for (int ni = 0; ni < 4; ++ni) {
    int col = bn * 128 + wn * 64 + ni * 16 + lr;
    float sc = (col >= 512 && col < 768) ? L2E2 : L2E;
    float bias = (bih[col] + bhh[col]) * sc;
#pragma unroll
    for (int mi = 0; mi < 4; ++mi) {
#pragma unroll
      for (int r = 0; r < 4; ++r) {
        int rowg = bm * 128 + wm * 64 + mi * 16 + lk * 4 + r;
        int t = rowg & 1023, bb = rowg >> 10;
        P[(size_t)((t << 5) + bb) * 1024 + col] = (f16)(acc[mi][ni][r] + bias);
      }
    }
  }
}

// ---------------- LSTM recurrence: 8 WGs = (unit, batch-half), fp8 MFMA, weights in VGPRs ----------------
__global__ __launch_bounds__(512, 2) void lstm_rec2(const unsigned char* __restrict__ whh8,
                                                    const f16* __restrict__ Pall,
                                                    const float* __restrict__ h0m,
                                                    const float* __restrict__ c0m,
                                                    const float* __restrict__ h0b,
                                                    const float* __restrict__ c0b,
                                                    f16* __restrict__ hid4) {
  const int wg = blockIdx.x;
  const int u = wg >> 1, q = wg & 1;
  const int dir = u & 1;
  const int tid = threadIdx.x;
  const int l = tid & 63, w = tid >> 6;
  const int lr = l & 15, lk = l >> 4;
  const int xr = (lr & 7) << 3;  // read-side swizzle (row = lr)

  __shared__ __align__(16) char hbuf[2][4096];  // [16 rows][256 k] fp8, XOR-swizzled

  // ---- load B-fragments (weights, fp8) into registers: 64 x 8B = 128 VGPR ----
  long long Bf[8][8];  // [ks][nt]
  const unsigned char* wbase = whh8 + ((size_t)u << 18);
#pragma unroll
  for (int nt = 0; nt < 8; ++nt) {
    int n = w * 32 + ((nt & 1) << 4) + lr + ((nt >> 1) << 8);
#pragma unroll
    for (int ks = 0; ks < 8; ++ks)
      Bf[ks][nt] = *(const long long*)(wbase + (size_t)n * 256 + ks * 32 + lk * 8);
  }

  // ---- init c state and h0 into hbuf[0] ----
  const float* h0 = (u < 2 ? h0m : h0b) + (size_t)dir * BATCH * HID;
  const float* c0 = (u < 2 ? c0m : c0b) + (size_t)dir * BATCH * HID;
  float cst[8];
#pragma unroll
  for (int r = 0; r < 4; ++r) {
    int brow = lk * 4 + r;
    int bglob = q * 16 + brow;
    int wxr = (brow & 7) << 3;
#pragma unroll
    for (int jj = 0; jj < 2; ++jj) {
      int j = w * 32 + jj * 16 + lr;
      cst[r * 2 + jj] = c0[bglob * HID + j];
      float hv = h0[bglob * HID + j];
      int pk = PK_FP8(hv, hv);
      hbuf[0][brow * 256 + (j ^ wxr)] = (char)(pk & 0xff);
    }
  }

  // ---- preload P for s=0 ----
  const f16* Pu = Pall + ((size_t)u << 25);
  f16 Pv[32];
  {
    int t0 = dir ? (S_LEN - 1) : 0;
#pragma unroll
    for (int nt = 0; nt < 8; ++nt) {
      int n = w * 32 + ((nt & 1) << 4) + lr + ((nt >> 1) << 8);
#pragma unroll
      for (int r = 0; r < 4; ++r)
        Pv[nt * 4 + r] = Pu[((size_t)t0 * 32 + q * 16 + lk * 4 + r) * 1024 + n];
    }
  }
  __syncthreads();

  for (int s = 0; s < S_LEN; ++s) {
    const int t = dir ? (S_LEN - 1 - s) : s;
    const int sp = s & 1;

    // prefetch next-step P into Pn (lands during mfma+gates)
    f16 Pn[32];
    {
      int s2 = (s + 1 < S_LEN) ? s + 1 : s;
      int t2 = dir ? (S_LEN - 1 - s2) : s2;
#pragma unroll
      for (int nt = 0; nt < 8; ++nt) {
        int n = w * 32 + ((nt & 1) << 4) + lr + ((nt >> 1) << 8);
#pragma unroll
        for (int r = 0; r < 4; ++r)
          Pn[nt * 4 + r] = Pu[((size_t)t2 * 32 + q * 16 + lk * 4 + r) * 1024 + n];
      }
    }

    // acc init from Pv (pre-scaled z from input projection)
    f32x4 acc[8];
#pragma unroll
    for (int nt = 0; nt < 8; ++nt)
#pragma unroll
      for (int r = 0; r < 4; ++r)
        acc[nt][r] = (float)Pv[nt * 4 + r];

    // z += whh * h : 64 fp8 MFMAs, A from swizzled LDS, B from registers
    const char* hb_rd = &hbuf[sp][lr * 256];
#pragma unroll
    for (int ks = 0; ks < 8; ++ks) {
      long long Afk = *(const long long*)(hb_rd + ((ks * 32 + lk * 8) ^ xr));
#pragma unroll
      for (int nt = 0; nt < 8; ++nt)
        acc[nt] = __builtin_amdgcn_mfma_f32_16x16x32_fp8_fp8(Afk, Bf[ks][nt], acc[nt], 0, 0, 0);
    }

    // gates fully in-register; z pre-scaled by log2e (g by 2*log2e)
#pragma unroll
    for (int r = 0; r < 4; ++r) {
      int brow = lk * 4 + r;
      int wxr = (brow & 7) << 3;
      float h_[2];
#pragma unroll
      for (int jj = 0; jj < 2; ++jj) {
        float zi = acc[0 + jj][r], zf = acc[2 + jj][r], zg = acc[4 + jj][r], zo = acc[6 + jj][r];
        float ei = EXP2(-zi), ef = EXP2(-zf), eg = EXP2(-zg), eo = EXP2(-zo);
        float di = 1.f + ei, df = 1.f + ef, dg = 1.f + eg, dof = 1.f + eo;
        float r1 = RCP(di * df);
        float si = r1 * df, sf = r1 * di;
        float r2 = RCP(dg * dof);
        float tg = 2.f * (r2 * dof) - 1.f, so = r2 * dg;
        float c = sf * cst[r * 2 + jj] + si * tg;
        cst[r * 2 + jj] = c;
        float ec = EXP2(-L2E2 * c);
        float th = 2.f * RCP(1.f + ec) - 1.f;
        h_[jj] = so * th;
      }
      int j0 = w * 32 + lr;
      int pk = PK_FP8(h_[0], h_[1]);
      char* hb = &hbuf[sp ^ 1][brow * 256];
      hb[j0 ^ wxr] = (char)(pk & 0xff);
      hb[(j0 + 16) ^ wxr] = (char)((pk >> 8) & 0xff);
      size_t hidx = ((size_t)(q * 16 + brow) << 20) + ((size_t)t << 10) + u * 256;
      hid4[hidx + j0] = (f16)h_[0];
      hid4[hidx + j0 + 16] = (f16)h_[1];
    }
    __syncthreads();
#pragma unroll
    for (int i = 0; i < 32; ++i) Pv[i] = Pn[i];
  }
}

// ---------------- emissions ----------------
__global__ __launch_bounds__(256) void emis_kernel(const f16* __restrict__ hid4,
                                                   const f16* __restrict__ wtag,
                                                   const float* __restrict__ btag,
                                                   const f16* __restrict__ wbin,
                                                   const float* __restrict__ bbin,
                                                   float* __restrict__ emis,
                                                   float* __restrict__ emisb) {
  const int tid = threadIdx.x;
  const int rl = tid >> 4, n = tid & 15;
  const size_t row = (size_t)blockIdx.x * 16 + rl;
  const f16x8* hv = (const f16x8*)(hid4 + row * 1024);
  const f16x8* wv = (const f16x8*)(wtag + n * 1024);
  float acc = btag[n];
#pragma unroll 8
  for (int kc = 0; kc < 128; ++kc) acc = dot8(wv[kc], hv[kc], acc);
  emis[row * 16 + n] = acc;
  if (n < 5) {
    const f16x8* hv2 = (const f16x8*)(hid4 + row * 1024 + 512);
    const f16x8* wv2 = (const f16x8*)(wbin + (size_t)n * 512);
    float a2 = bbin[n];
#pragma unroll 8
    for (int kc = 0; kc < 64; ++kc) a2 = dot8(wv2[kc], hv2[kc], a2);
    emisb[row * 5 + n] = a2;
  }
}

// ---------------- CRF forward (logZ) — round-1 proven version (+ as_ init) ----------------
__global__ __launch_bounds__(64) void crf_logz(const float* __restrict__ emis,
                                               const float* __restrict__ trans,
                                               const float* __restrict__ emisb,
                                               const float* __restrict__ transb,
                                               const float* __restrict__ mask,
                                               float* __restrict__ outLogZ) {
  const int crf = blockIdx.x >> 5, b = blockIdx.x & 31;
  const int NTc = crf ? 5 : 16;
  const float* __restrict__ E = crf ? emisb : emis;
  const float* __restrict__ T = crf ? transb : trans;
  const int lane = threadIdx.x;
  const int j = lane >> 2, p = lane & 3;
  const bool jv = (j < NTc);
  float Tc[4];
#pragma unroll
  for (int ii = 0; ii < 4; ++ii) {
    int i = p * 4 + ii;
    Tc[ii] = (jv && i < NTc) ? T[i * NTc + j] : -1e30f;
  }
  __shared__ float as_[16];
  if (lane < 16) as_[lane] = -1e30f;
  float alpha = 0.f;
  __syncthreads();
  if (jv && p == 0) {
    alpha = T[1 * NTc + j] + E[(size_t)(b << 10) * NTc + j];  // SOS=1, t=0
    as_[j] = alpha;
  }
  __syncthreads();
  for (int t = 1; t < S_LEN; ++t) {
    float m_t = mask[(b << 10) + t];
    float v[4];
#pragma unroll
    for (int ii = 0; ii < 4; ++ii) {
      int i = p * 4 + ii;
      v[ii] = (jv && i < NTc) ? (as_[i] + Tc[ii]) : -1e30f;
    }
    float mx = fmaxf(fmaxf(v[0], v[1]), fmaxf(v[2], v[3]));
    mx = fmaxf(mx, __shfl_xor(mx, 1, 4));
    mx = fmaxf(mx, __shfl_xor(mx, 2, 4));
    float ssum = __expf(v[0] - mx) + __expf(v[1] - mx) + __expf(v[2] - mx) + __expf(v[3] - mx);
    ssum += __shfl_xor(ssum, 1, 4);
    ssum += __shfl_xor(ssum, 2, 4);
    if (jv && p == 0) {
      float e_tj = E[((size_t)(b << 10) + t) * NTc + j];
      float newv = e_tj + mx + __logf(ssum);
      alpha = (m_t > 0.5f) ? newv : alpha;
    }
    __syncthreads();
    if (jv && p == 0) as_[j] = alpha;
    __syncthreads();
  }
  if (lane == 0) {
    float mx = -1e30f;
    for (int jj = 0; jj < NTc; ++jj) mx = fmaxf(mx, as_[jj] + T[jj * NTc + 2]);  // EOS=2
    float ssum = 0.f;
    for (int jj = 0; jj < NTc; ++jj) ssum += __expf(as_[jj] + T[jj * NTc + 2] - mx);
    outLogZ[crf * 32 + b] = mx + __logf(ssum);
  }
}

// ---------------- CRF gold score ----------------
__global__ __launch_bounds__(64) void crf_score(const float* __restrict__ emis,
                                                const float* __restrict__ trans,
                                                const float* __restrict__ emisb,
                                                const float* __restrict__ transb,
                                                const float* __restrict__ mask,
                                                const int* __restrict__ tags,
                                                const int* __restrict__ tagsb,
                                                float* __restrict__ outScore) {
  const int crf = blockIdx.x >> 5, b = blockIdx.x & 31;
  const int NTc = crf ? 5 : 16;
  const float* __restrict__ E = crf ? emisb : emis;
  const float* __restrict__ T = crf ? transb : trans;
  const int* __restrict__ tg = (crf ? tagsb : tags) + (b << 10);
  const float* __restrict__ mk = mask + (b << 10);
  const int lane = threadIdx.x;
  float s = 0.f, cnt = 0.f;
  for (int t = lane; t < S_LEN; t += 64) {
    float m = mk[t];
    cnt += m;
    if (t >= 1 && m > 0.5f)
      s += E[((size_t)(b << 10) + t) * NTc + tg[t]] + T[tg[t - 1] * NTc + tg[t]];
  }
#pragma unroll
  for (int off = 32; off >= 1; off >>= 1) {
    s += __shfl_down(s, off);
    cnt += __shfl_down(cnt, off);
  }
  if (lane == 0) {
    int L = (int)(cnt + 0.5f);
    int t0 = tg[0];
    float tot = T[1 * NTc + t0] + E[(size_t)(b << 10) * NTc + t0] + s + T[tg[L - 1] * NTc + 2];
    outScore[crf * 32 + b] = tot;
  }
}

__global__ void finalk(const float* __restrict__ logZ, const float* __restrict__ score,
                       float* __restrict__ out) {
  int j = threadIdx.x;
  if (j < 2) {
    float a = 0.f;
    for (int b = 0; b < 32; ++b) a += logZ[j * 32 + b] - score[j * 32 + b];
    out[j] = a;
  }
}

extern "C" void kernel_launch(void* const* d_in, const int* in_sizes, int n_in,
                              void* d_out, int out_size, void* d_ws, size_t ws_size,
                              hipStream_t stream) {
  const float* x       = (const float*)d_in[0];
  const float* xbin    = (const float*)d_in[1];
  const float* mask    = (const float*)d_in[2];
  const int*   tags    = (const int*)d_in[3];
  const int*   tagsb   = (const int*)d_in[4];
  const float* trans   = (const float*)d_in[5];
  const float* transb  = (const float*)d_in[6];
  const float* w2f_ih  = (const float*)d_in[7];
  const float* w2f_hh  = (const float*)d_in[8];
  const float* b2f_ih  = (const float*)d_in[9];
  const float* b2f_hh  = (const float*)d_in[10];
  const float* w2b_ih  = (const float*)d_in[11];
  const float* w2b_hh  = (const float*)d_in[12];
  const float* b2b_ih  = (const float*)d_in[13];
  const float* b2b_hh  = (const float*)d_in[14];
  const float* w_bin   = (const float*)d_in[15];
  const float* bb_bin  = (const float*)d_in[16];
  const float* w1f_ih  = (const float*)d_in[17];
  const float* w1f_hh  = (const float*)d_in[18];
  const float* b1f_ih  = (const float*)d_in[19];
  const float* b1f_hh  = (const float*)d_in[20];
  const float* w1b_ih  = (const float*)d_in[21];
  const float* w1b_hh  = (const float*)d_in[22];
  const float* b1b_ih  = (const float*)d_in[23];
  const float* b1b_hh  = (const float*)d_in[24];
  const float* w_tag   = (const float*)d_in[25];
  const float* b_tag   = (const float*)d_in[26];
  const float* h0_bin  = (const float*)d_in[27];
  const float* c0_bin  = (const float*)d_in[28];
  const float* h0_main = (const float*)d_in[29];
  const float* c0_main = (const float*)d_in[30];

  char* ws = (char*)d_ws;
  f16* P      = (f16*)(ws);                          // 4 x 33554432 f16 = 256 MiB
  f16* hid4   = (f16*)(ws + 268435456);              // 64 MiB
  unsigned char* whh8 = (unsigned char*)(ws + 335544320);  // 4 x 262144 B = 1 MiB
  f16* wtag   = (f16*)(ws + 336592896);              // 16384 f16
  f16* wbin   = (f16*)(ws + 336625664);              // 2560 f16
  float* emis  = (float*)(ws + 336630784);           // 32768*16 f32
  float* emisb = (float*)(ws + 338727936);           // 32768*5 f32
  float* logZ  = (float*)(ws + 339383296);           // 64 f32
  float* score = (float*)(ws + 339383552);           // 64 f32

  // weight preps
  cvt_whh_fp8<<<512, 256, 0, stream>>>(w1f_hh, whh8 + 0 * 262144);
  cvt_whh_fp8<<<512, 256, 0, stream>>>(w1b_hh, whh8 + 1 * 262144);
  cvt_whh_fp8<<<512, 256, 0, stream>>>(w2f_hh, whh8 + 2 * 262144);
  cvt_whh_fp8<<<512, 256, 0, stream>>>(w2b_hh, whh8 + 3 * 262144);
  cvt_f32_f16<<<16, 256, 0, stream>>>(w_tag, wtag, 4096);
  cvt_f32_f16<<<3, 256, 0, stream>>>(w_bin, wbin, 640);

  // input projections (log2e-scaled): units 0..3 = main_f, main_b, bin_f, bin_b
  dim3 gg(8, 256);
  proj_gemm<<<gg, 256, 0, stream>>>(x, w1f_ih, b1f_ih, b1f_hh, P + (size_t)0 * 33554432, 512);
  proj_gemm<<<gg, 256, 0, stream>>>(x, w1b_ih, b1b_ih, b1b_hh, P + (size_t)1 * 33554432, 512);
  proj_gemm<<<gg, 256, 0, stream>>>(xbin, w2f_ih, b2f_ih, b2f_hh, P + (size_t)2 * 33554432, 1536);
  proj_gemm<<<gg, 256, 0, stream>>>(xbin, w2b_ih, b2b_ih, b2b_hh, P + (size_t)3 * 33554432, 1536);

  lstm_rec2<<<8, 512, 0, stream>>>(whh8, P, h0_main, c0_main, h0_bin, c0_bin, hid4);
  emis_kernel<<<2048, 256, 0, stream>>>(hid4, wtag, b_tag, wbin, bb_bin, emis, emisb);
  crf_logz<<<64, 64, 0, stream>>>(emis, trans, emisb, transb, mask, logZ);
  crf_score<<<64, 64, 0, stream>>>(emis, trans, emisb, transb, mask, tags, tagsb, score);
  finalk<<<1, 64, 0, stream>>>(logZ, score, (float*)d_out);
}